// Round 2
// baseline (768.282 us; speedup 1.0000x reference)
//
#include <hip/hip_runtime.h>
#include <hip/hip_bf16.h>

#define DIM 128
#define LVL 8

typedef unsigned int u32;

__device__ __forceinline__ float sigf(float x) { return 1.f / (1.f + __expf(-x)); }
__device__ __forceinline__ float tanhfast(float x) { return 1.f - 2.f / (__expf(2.f * x) + 1.f); }

// ---- level offsets: ofs[d] = first index with depth >= d (depth is sorted) ----
__global__ void k_levels(const int* __restrict__ depth, int n, int* __restrict__ ofs) {
  int d = threadIdx.x;
  if (d > LVL) return;
  int lo = 0, hi = n;
  while (lo < hi) { int mid = (lo + hi) >> 1; if (depth[mid] < d) lo = mid + 1; else hi = mid; }
  ofs[d] = lo;
}

// ---- per-node child counts ----
__global__ void k_count(const int* __restrict__ parent, int n, int* __restrict__ nchild) {
  int j = blockIdx.x * blockDim.x + threadIdx.x;
  if (j >= n) return;
  int p = parent[j];
  if (p >= 0 && p < n) atomicAdd(&nchild[p], 1);
}

// ---- xf = x @ Wfx (f32), 32 rows/block, W staged in two k-chunks of 64 ----
__global__ __launch_bounds__(256) void k_xf(const float* __restrict__ x, const float* __restrict__ W,
                                            float* __restrict__ xf, int n) {
  __shared__ float xs[32][DIM];   // 16 KB
  __shared__ float wsb[64][DIM];  // 32 KB
  int row0 = blockIdx.x * 32;
  if (row0 >= n) return;
  int nrows = min(32, n - row0);
  int tid = threadIdx.x;
  for (int idx = tid; idx < 32 * DIM / 4; idx += 256) {
    int r = idx >> 5, c4 = (idx & 31) * 4;
    float4 v = make_float4(0.f, 0.f, 0.f, 0.f);
    if (r < nrows) v = *(const float4*)(x + (size_t)(row0 + r) * DIM + c4);
    *(float4*)&xs[r][c4] = v;
  }
  int c = tid & 63;
  int rg = (tid >> 6) * 8;
  float a0[8], a1[8];
  #pragma unroll
  for (int q = 0; q < 8; ++q) { a0[q] = 0.f; a1[q] = 0.f; }
  for (int kc = 0; kc < 2; ++kc) {
    __syncthreads();
    for (int idx = tid; idx < 64 * DIM / 4; idx += 256) {
      int r = idx >> 5, c4 = (idx & 31) * 4;
      *(float4*)&wsb[r][c4] = *(const float4*)(W + (size_t)(kc * 64 + r) * DIM + c4);
    }
    __syncthreads();
    #pragma unroll 4
    for (int k = 0; k < 64; ++k) {
      float2 wv = *(const float2*)&wsb[k][2 * c];
      #pragma unroll
      for (int q = 0; q < 8; ++q) {
        float s = xs[rg + q][kc * 64 + k];
        a0[q] += s * wv.x; a1[q] += s * wv.y;
      }
    }
  }
  #pragma unroll
  for (int q = 0; q < 8; ++q) {
    int r = rg + q;
    if (r < nrows) {
      float2 st; st.x = a0[q]; st.y = a1[q];
      *(float2*)(xf + (size_t)(row0 + r) * DIM + 2 * c) = st;
    }
  }
}

// ---- per child j (depth d+1): f=sigmoid(xf[p]+h_j@Wfh); hsum[p]+=h_j; fcsum[p]+=f*c_j ----
__global__ __launch_bounds__(256) void k_child(const float* __restrict__ h, const float* __restrict__ cbuf,
    const float* __restrict__ xf, const float* __restrict__ Wfh, const int* __restrict__ parent,
    const int* __restrict__ ofs, float* __restrict__ hsum, float* __restrict__ fcsum, int d) {
  __shared__ float hs[16][DIM];   // 8 KB
  __shared__ float wsb[64][DIM];  // 32 KB
  __shared__ int ps[16];
  __shared__ int s_uni;
  int c0 = ofs[d + 1], c1 = ofs[d + 2];
  int row0 = c0 + (int)blockIdx.x * 16;
  if (row0 >= c1) return;
  int nrows = min(16, c1 - row0);
  int tid = threadIdx.x;
  for (int idx = tid; idx < 16 * DIM / 4; idx += 256) {
    int r = idx >> 5, c4 = (idx & 31) * 4;
    float4 v = make_float4(0.f, 0.f, 0.f, 0.f);
    if (r < nrows) v = *(const float4*)(h + (size_t)(row0 + r) * DIM + c4);
    *(float4*)&hs[r][c4] = v;
  }
  if (tid < 16) ps[tid] = (tid < nrows) ? parent[row0 + tid] : -1;
  __syncthreads();
  if (tid == 0) {
    int u = 1, p0 = ps[0];
    for (int r = 1; r < nrows; ++r) if (ps[r] != p0) { u = 0; break; }
    s_uni = u;
  }
  int c = tid & 63;
  int rg = (tid >> 6) * 4;
  float a0[4], a1[4];
  #pragma unroll
  for (int q = 0; q < 4; ++q) { a0[q] = 0.f; a1[q] = 0.f; }
  for (int kc = 0; kc < 2; ++kc) {
    __syncthreads();
    for (int idx = tid; idx < 64 * DIM / 4; idx += 256) {
      int r = idx >> 5, c4 = (idx & 31) * 4;
      *(float4*)&wsb[r][c4] = *(const float4*)(Wfh + (size_t)(kc * 64 + r) * DIM + c4);
    }
    __syncthreads();
    #pragma unroll 4
    for (int k = 0; k < 64; ++k) {
      float2 wv = *(const float2*)&wsb[k][2 * c];
      #pragma unroll
      for (int q = 0; q < 4; ++q) {
        float s = hs[rg + q][kc * 64 + k];
        a0[q] += s * wv.x; a1[q] += s * wv.y;
      }
    }
  }
  __syncthreads();
  if (s_uni) {
    int p = ps[0];
    if (tid < DIM) {
      float s = 0.f;
      #pragma unroll
      for (int r = 0; r < 16; ++r) s += hs[r][tid];
      atomicAdd(&hsum[(size_t)p * DIM + tid], s);
    }
    float2 xfv = *(const float2*)(xf + (size_t)p * DIM + 2 * c);
    __syncthreads();
    #pragma unroll
    for (int q = 0; q < 4; ++q) {
      int r = rg + q;
      float f0 = 0.f, f1 = 0.f;
      if (r < nrows) {
        float2 cv = *(const float2*)(cbuf + (size_t)(row0 + r) * DIM + 2 * c);
        f0 = sigf(xfv.x + a0[q]) * cv.x;
        f1 = sigf(xfv.y + a1[q]) * cv.y;
      }
      hs[r][2 * c] = f0;
      hs[r][2 * c + 1] = f1;
    }
    __syncthreads();
    if (tid < DIM) {
      float s = 0.f;
      #pragma unroll
      for (int r = 0; r < 16; ++r) s += hs[r][tid];
      atomicAdd(&fcsum[(size_t)p * DIM + tid], s);
    }
  } else {
    #pragma unroll
    for (int q = 0; q < 4; ++q) {
      int r = rg + q;
      if (r < nrows) {
        int p = ps[r];
        float2 xfv = *(const float2*)(xf + (size_t)p * DIM + 2 * c);
        float2 cv = *(const float2*)(cbuf + (size_t)(row0 + r) * DIM + 2 * c);
        atomicAdd(&fcsum[(size_t)p * DIM + 2 * c],     sigf(xfv.x + a0[q]) * cv.x);
        atomicAdd(&fcsum[(size_t)p * DIM + 2 * c + 1], sigf(xfv.y + a1[q]) * cv.y);
      }
    }
    for (int idx = tid; idx < nrows * DIM; idx += 256) {
      int r = idx >> 7, k = idx & 127;
      atomicAdd(&hsum[(size_t)ps[r] * DIM + k], hs[r][k]);
    }
  }
}

// ---- per node v (depth d): iou = x@Wioux + hsum@Wiouh; gates; leaf override ----
__global__ __launch_bounds__(256) void k_node(const float* __restrict__ x, const float* __restrict__ Wioux,
    const float* __restrict__ Wiouh, const float* __restrict__ hsum, const float* __restrict__ fcsum,
    const int* __restrict__ nchild, const int* __restrict__ ofs,
    float* __restrict__ h, float* __restrict__ cbuf, int d) {
  __shared__ float xs[16][DIM];   // 8 KB
  __shared__ float hss[16][DIM];  // 8 KB
  __shared__ float wsb[64][DIM];  // 32 KB
  int v0 = ofs[d], v1 = ofs[d + 1];
  int row0 = v0 + (int)blockIdx.x * 16;
  if (row0 >= v1) return;
  int nrows = min(16, v1 - row0);
  int tid = threadIdx.x;
  for (int idx = tid; idx < 16 * DIM / 4; idx += 256) {
    int r = idx >> 5, c4 = (idx & 31) * 4;
    float4 xv = make_float4(0.f, 0.f, 0.f, 0.f);
    float4 gv = make_float4(0.f, 0.f, 0.f, 0.f);
    if (r < nrows) {
      xv = *(const float4*)(x + (size_t)(row0 + r) * DIM + c4);
      gv = *(const float4*)(hsum + (size_t)(row0 + r) * DIM + c4);
    }
    *(float4*)&xs[r][c4] = xv;
    *(float4*)&hss[r][c4] = gv;
  }
  int c = tid & 63;
  int rg = (tid >> 6) * 4;
  float acc[3][2][4];
  #pragma unroll
  for (int ci = 0; ci < 3; ++ci)
    #pragma unroll
    for (int g = 0; g < 2; ++g)
      #pragma unroll
      for (int q = 0; q < 4; ++q) acc[ci][g][q] = 0.f;

  for (int ci = 0; ci < 3; ++ci) {
    // x @ Wioux[:, ci*DIM : (ci+1)*DIM]
    for (int kc = 0; kc < 2; ++kc) {
      __syncthreads();
      for (int idx = tid; idx < 64 * DIM / 4; idx += 256) {
        int r = idx >> 5, c4 = (idx & 31) * 4;
        *(float4*)&wsb[r][c4] = *(const float4*)(Wioux + (size_t)(kc * 64 + r) * (3 * DIM) + ci * DIM + c4);
      }
      __syncthreads();
      #pragma unroll 4
      for (int k = 0; k < 64; ++k) {
        float2 wv = *(const float2*)&wsb[k][2 * c];
        #pragma unroll
        for (int q = 0; q < 4; ++q) {
          float s = xs[rg + q][kc * 64 + k];
          acc[ci][0][q] += s * wv.x; acc[ci][1][q] += s * wv.y;
        }
      }
    }
    // hsum @ Wiouh[:, ci*DIM : (ci+1)*DIM]
    for (int kc = 0; kc < 2; ++kc) {
      __syncthreads();
      for (int idx = tid; idx < 64 * DIM / 4; idx += 256) {
        int r = idx >> 5, c4 = (idx & 31) * 4;
        *(float4*)&wsb[r][c4] = *(const float4*)(Wiouh + (size_t)(kc * 64 + r) * (3 * DIM) + ci * DIM + c4);
      }
      __syncthreads();
      #pragma unroll 4
      for (int k = 0; k < 64; ++k) {
        float2 wv = *(const float2*)&wsb[k][2 * c];
        #pragma unroll
        for (int q = 0; q < 4; ++q) {
          float s = hss[rg + q][kc * 64 + k];
          acc[ci][0][q] += s * wv.x; acc[ci][1][q] += s * wv.y;
        }
      }
    }
  }
  #pragma unroll
  for (int q = 0; q < 4; ++q) {
    int r = rg + q;
    if (r >= nrows) continue;
    int gr = row0 + r;
    bool leaf = (nchild[gr] == 0);
    float2 fcv = *(const float2*)(fcsum + (size_t)gr * DIM + 2 * c);
    float i0 = sigf(acc[0][0][q]), i1 = sigf(acc[0][1][q]);
    float o0 = sigf(acc[1][0][q]), o1 = sigf(acc[1][1][q]);
    float u0 = tanhfast(acc[2][0][q]), u1 = tanhfast(acc[2][1][q]);
    float ci0 = fcv.x + i0 * u0, ci1 = fcv.y + i1 * u1;
    float xv0 = xs[r][2 * c], xv1 = xs[r][2 * c + 1];
    float hv0 = leaf ? xv0 : o0 * tanhfast(ci0);
    float hv1 = leaf ? xv1 : o1 * tanhfast(ci1);
    float cv0 = leaf ? tanhfast(xv0) : ci0;
    float cv1 = leaf ? tanhfast(xv1) : ci1;
    float2 hst; hst.x = hv0; hst.y = hv1;
    *(float2*)(h + (size_t)gr * DIM + 2 * c) = hst;
    float2 cst; cst.x = cv0; cst.y = cv1;
    *(float2*)(cbuf + (size_t)gr * DIM + 2 * c) = cst;
  }
}

extern "C" void kernel_launch(void* const* d_in, const int* in_sizes, int n_in,
                              void* d_out, int out_size, void* d_ws, size_t ws_size,
                              hipStream_t stream) {
  const float* x    = (const float*)d_in[0];
  const int* parent = (const int*)d_in[1];
  const int* depth  = (const int*)d_in[2];
  const float* Wioux = (const float*)d_in[3];
  const float* Wiouh = (const float*)d_in[4];
  const float* Wfx   = (const float*)d_in[5];
  const float* Wfh   = (const float*)d_in[6];
  int n = in_sizes[0] / DIM;
  float* h = (float*)d_out;

  float* xf    = (float*)d_ws;
  float* cbuf  = xf    + (size_t)n * DIM;
  float* hsum  = cbuf  + (size_t)n * DIM;
  float* fcsum = hsum  + (size_t)n * DIM;
  int*   nchild = (int*)(fcsum + (size_t)n * DIM);
  int*   ofs    = nchild + n;

  // zero hsum, fcsum, nchild (contiguous)
  hipMemsetAsync(hsum, 0, (size_t)2 * n * DIM * sizeof(float) + (size_t)n * sizeof(int), stream);
  k_levels<<<1, 32, 0, stream>>>(depth, n, ofs);
  k_count<<<(n + 255) / 256, 256, 0, stream>>>(parent, n, nchild);
  k_xf<<<(n + 31) / 32, 256, 0, stream>>>(x, Wfx, xf, n);

  int gblocks = (n + 15) / 16;
  for (int d = LVL - 1; d >= 0; --d) {
    if (d < LVL - 1)
      k_child<<<gblocks, 256, 0, stream>>>(h, cbuf, xf, Wfh, parent, ofs, hsum, fcsum, d);
    k_node<<<gblocks, 256, 0, stream>>>(x, Wioux, Wiouh, hsum, fcsum, nchild, ofs, h, cbuf, d);
  }
}

// Round 3
// 554.338 us; speedup vs baseline: 1.3859x; 1.3859x over previous
//
#include <hip/hip_runtime.h>
#include <hip/hip_bf16.h>

#define DIM 128
#define LVL 8

typedef unsigned int u32;
typedef unsigned short u16;

using bf16x8 = __attribute__((ext_vector_type(8))) short;
using f32x4  = __attribute__((ext_vector_type(4))) float;

__device__ __forceinline__ float bf2f(u16 u) { union { u32 i; float f; } v; v.i = ((u32)u) << 16; return v.f; }
__device__ __forceinline__ u16 f2bf(float f) { __hip_bfloat16 b = __float2bfloat16(f); return *reinterpret_cast<u16*>(&b); }
__device__ __forceinline__ u32 pk2(float lo, float hi) { return (u32)f2bf(lo) | ((u32)f2bf(hi) << 16); }
__device__ __forceinline__ float sigf(float x) { return 1.f / (1.f + __expf(-x)); }
__device__ __forceinline__ float tanhfast(float x) { return 1.f - 2.f / (__expf(2.f * x) + 1.f); }

// ---- level offsets: ofs[d] = first index with depth >= d ----
__global__ void k_levels(const int* __restrict__ depth, int n, int* __restrict__ ofs) {
  int d = threadIdx.x;
  if (d > LVL) return;
  int lo = 0, hi = n;
  while (lo < hi) { int mid = (lo + hi) >> 1; if (depth[mid] < d) lo = mid + 1; else hi = mid; }
  ofs[d] = lo;
}

// ---- haschild via benign-race plain store (replaces contended atomicAdd) ----
__global__ void k_mark(const int* __restrict__ parent, int n, int* __restrict__ haschild) {
  int j = blockIdx.x * blockDim.x + threadIdx.x;
  if (j >= n) return;
  int p = parent[j];
  if (p >= 0 && p < n) haschild[p] = 1;
}

// ---- WcT[c][k] = bf16 of combined [Wioux | Wfx] column c, c in [0,512) ----
__global__ void k_prep(const float* __restrict__ Wioux, const float* __restrict__ Wfx,
                       u16* __restrict__ WcT) {
  int i = blockIdx.x * 256 + threadIdx.x;
  if (i >= 512 * 128) return;
  int c = i >> 7, k = i & 127;
  float v = (c < 384) ? Wioux[(size_t)k * 384 + c] : Wfx[(size_t)k * 128 + (c - 384)];
  WcT[(size_t)c * 128 + k] = f2bf(v);
}

// ---- xi_xf = x @ [Wioux|Wfx]  (MFMA bf16, f32 acc, bf16 out) ----
// grid: (M/64, 4). Block: 256 thr = 4 waves; wave w -> rows [w*16,+16), all 128 cols of chunk.
__global__ __launch_bounds__(256) void k_big(const float* __restrict__ x, const u16* __restrict__ WcT,
                                             u16* __restrict__ xi, int n) {
  __shared__ __align__(16) char smem[49152];
  char* xsb = smem;             // 64 x 128 bf16, swizzled (16 KB)
  char* wtb = smem + 16384;     // 128 x 128 bf16 = W^T chunk, swizzled (32 KB)
  int tid = threadIdx.x;
  int wave = tid >> 6, lane = tid & 63;
  int m = lane & 15, kg = lane >> 4;
  int row0 = blockIdx.x * 64;
  int col0 = blockIdx.y * 128;

  // stage x rows (f32 -> bf16, swizzled)
  for (int i = tid; i < 64 * 16; i += 256) {
    int r = i >> 4, c8 = (i & 15) * 8;
    int gr = row0 + r;
    uint4 o = make_uint4(0u, 0u, 0u, 0u);
    if (gr < n) {
      float4 a = *(const float4*)(x + (size_t)gr * DIM + c8);
      float4 b = *(const float4*)(x + (size_t)gr * DIM + c8 + 4);
      o = make_uint4(pk2(a.x, a.y), pk2(a.z, a.w), pk2(b.x, b.y), pk2(b.z, b.w));
    }
    int byte = r * 256 + ((c8 * 2) ^ ((r & 7) << 4));
    *(uint4*)(xsb + byte) = o;
  }
  // stage W^T chunk (bf16, swizzled): row cl = output col, 128 k-bytes
  for (int i = tid; i < 128 * 16; i += 256) {
    int cl = i >> 4, k8 = (i & 15) * 8;
    uint4 v = *(const uint4*)(WcT + (size_t)(col0 + cl) * 128 + k8);
    int byte = cl * 256 + ((k8 * 2) ^ ((cl & 7) << 4));
    *(uint4*)(wtb + byte) = v;
  }
  __syncthreads();

  f32x4 acc[8];
  #pragma unroll
  for (int nt = 0; nt < 8; ++nt) acc[nt] = (f32x4){0.f, 0.f, 0.f, 0.f};
  int arow = wave * 16 + m;
  #pragma unroll
  for (int kk = 0; kk < 4; ++kk) {
    int kbyte = kk * 64 + kg * 16;
    bf16x8 a = *(const bf16x8*)(xsb + arow * 256 + (kbyte ^ ((arow & 7) << 4)));
    #pragma unroll
    for (int nt = 0; nt < 8; ++nt) {
      int col = nt * 16 + m;
      bf16x8 b = *(const bf16x8*)(wtb + col * 256 + (kbyte ^ ((col & 7) << 4)));
      acc[nt] = __builtin_amdgcn_mfma_f32_16x16x32_bf16(a, b, acc[nt], 0, 0, 0);
    }
  }
  __syncthreads();

  // epilogue: transpose through LDS (rows of 132 f32 to dodge bank conflicts), store bf16
  float* dbuf = (float*)smem;   // 64 x 132 f32 = 33792 B
  #pragma unroll
  for (int nt = 0; nt < 8; ++nt) {
    #pragma unroll
    for (int r = 0; r < 4; ++r) {
      dbuf[(wave * 16 + kg * 4 + r) * 132 + nt * 16 + m] = acc[nt][r];
    }
  }
  __syncthreads();
  int r2 = tid >> 2, q = tid & 3;
  int gr = row0 + r2;
  if (gr < n) {
    const float* src = dbuf + r2 * 132 + q * 32;
    u16* dst = xi + (size_t)gr * 512 + col0 + q * 32;
    #pragma unroll
    for (int seg = 0; seg < 4; ++seg) {
      float4 a = *(const float4*)(src + seg * 8);
      float4 b = *(const float4*)(src + seg * 8 + 4);
      uint4 o = make_uint4(pk2(a.x, a.y), pk2(a.z, a.w), pk2(b.x, b.y), pk2(b.z, b.w));
      *(uint4*)(dst + seg * 8) = o;
    }
  }
}

// ---- per child j (depth d+1): f=sigmoid(xf[p]+h_j@Wfh); hsum[p]+=h_j; fcsum[p]+=f*c_j ----
__global__ __launch_bounds__(256) void k_child(const float* __restrict__ h, const float* __restrict__ cbuf,
    const u16* __restrict__ xi, const float* __restrict__ Wfh, const int* __restrict__ parent,
    const int* __restrict__ ofs, float* __restrict__ hsum, float* __restrict__ fcsum, int d) {
  __shared__ float hs[16][DIM];
  __shared__ float wsb[64][DIM];
  __shared__ int ps[16];
  __shared__ int s_uni;
  int c0 = ofs[d + 1], c1 = ofs[d + 2];
  int tid = threadIdx.x;
  int c = tid & 63;
  int rg = (tid >> 6) * 4;
  for (int row0 = c0 + (int)blockIdx.x * 16; row0 < c1; row0 += (int)gridDim.x * 16) {
    int nrows = min(16, c1 - row0);
    for (int idx = tid; idx < 16 * DIM / 4; idx += 256) {
      int r = idx >> 5, c4 = (idx & 31) * 4;
      float4 v = make_float4(0.f, 0.f, 0.f, 0.f);
      if (r < nrows) v = *(const float4*)(h + (size_t)(row0 + r) * DIM + c4);
      *(float4*)&hs[r][c4] = v;
    }
    if (tid < 16) ps[tid] = (tid < nrows) ? parent[row0 + tid] : -1;
    __syncthreads();
    if (tid == 0) {
      int u = 1, p0 = ps[0];
      for (int r = 1; r < nrows; ++r) if (ps[r] != p0) { u = 0; break; }
      s_uni = u;
    }
    float a0[4], a1[4];
    #pragma unroll
    for (int q = 0; q < 4; ++q) { a0[q] = 0.f; a1[q] = 0.f; }
    for (int kc = 0; kc < 2; ++kc) {
      __syncthreads();
      for (int idx = tid; idx < 64 * DIM / 4; idx += 256) {
        int r = idx >> 5, c4 = (idx & 31) * 4;
        *(float4*)&wsb[r][c4] = *(const float4*)(Wfh + (size_t)(kc * 64 + r) * DIM + c4);
      }
      __syncthreads();
      #pragma unroll 4
      for (int k = 0; k < 64; ++k) {
        float2 wv = *(const float2*)&wsb[k][2 * c];
        #pragma unroll
        for (int q = 0; q < 4; ++q) {
          float s = hs[rg + q][kc * 64 + k];
          a0[q] += s * wv.x; a1[q] += s * wv.y;
        }
      }
    }
    __syncthreads();
    if (s_uni) {
      int p = ps[0];
      if (tid < DIM) {
        float s = 0.f;
        #pragma unroll
        for (int r = 0; r < 16; ++r) s += hs[r][tid];
        atomicAdd(&hsum[(size_t)p * DIM + tid], s);
      }
      u32 xw = *(const u32*)(xi + (size_t)p * 512 + 384 + 2 * c);
      float xf0 = bf2f((u16)(xw & 0xffffu)), xf1 = bf2f((u16)(xw >> 16));
      __syncthreads();
      #pragma unroll
      for (int q = 0; q < 4; ++q) {
        int r = rg + q;
        float f0 = 0.f, f1 = 0.f;
        if (r < nrows) {
          float2 cv = *(const float2*)(cbuf + (size_t)(row0 + r) * DIM + 2 * c);
          f0 = sigf(xf0 + a0[q]) * cv.x;
          f1 = sigf(xf1 + a1[q]) * cv.y;
        }
        hs[r][2 * c] = f0;
        hs[r][2 * c + 1] = f1;
      }
      __syncthreads();
      if (tid < DIM) {
        float s = 0.f;
        #pragma unroll
        for (int r = 0; r < 16; ++r) s += hs[r][tid];
        atomicAdd(&fcsum[(size_t)p * DIM + tid], s);
      }
    } else {
      #pragma unroll
      for (int q = 0; q < 4; ++q) {
        int r = rg + q;
        if (r < nrows) {
          int p = ps[r];
          u32 xw = *(const u32*)(xi + (size_t)p * 512 + 384 + 2 * c);
          float2 cv = *(const float2*)(cbuf + (size_t)(row0 + r) * DIM + 2 * c);
          atomicAdd(&fcsum[(size_t)p * DIM + 2 * c],     sigf(bf2f((u16)(xw & 0xffffu)) + a0[q]) * cv.x);
          atomicAdd(&fcsum[(size_t)p * DIM + 2 * c + 1], sigf(bf2f((u16)(xw >> 16))     + a1[q]) * cv.y);
        }
      }
      for (int idx = tid; idx < nrows * DIM; idx += 256) {
        int r = idx >> 7, k = idx & 127;
        atomicAdd(&hsum[(size_t)ps[r] * DIM + k], hs[r][k]);
      }
    }
    __syncthreads();
  }
}

// ---- per node v (depth d): iou = xi[v] + hsum@Wiouh; gates; leaf override ----
__global__ __launch_bounds__(256) void k_node(const float* __restrict__ x,
    const float* __restrict__ Wiouh, const u16* __restrict__ xi,
    const float* __restrict__ hsum, const float* __restrict__ fcsum,
    const int* __restrict__ haschild, const int* __restrict__ ofs,
    float* __restrict__ h, float* __restrict__ cbuf, int d) {
  __shared__ float xs[16][DIM];
  __shared__ float hss[16][DIM];
  __shared__ float wsb[64][DIM];
  __shared__ int flags[16];
  __shared__ int s_any;
  int v0 = ofs[d], v1 = ofs[d + 1];
  int tid = threadIdx.x;
  int c = tid & 63;
  int rg = (tid >> 6) * 4;
  for (int row0 = v0 + (int)blockIdx.x * 16; row0 < v1; row0 += (int)gridDim.x * 16) {
    int nrows = min(16, v1 - row0);
    for (int idx = tid; idx < 16 * DIM / 4; idx += 256) {
      int r = idx >> 5, c4 = (idx & 31) * 4;
      float4 xv = make_float4(0.f, 0.f, 0.f, 0.f);
      float4 gv = make_float4(0.f, 0.f, 0.f, 0.f);
      if (r < nrows) {
        xv = *(const float4*)(x + (size_t)(row0 + r) * DIM + c4);
        gv = *(const float4*)(hsum + (size_t)(row0 + r) * DIM + c4);
      }
      *(float4*)&xs[r][c4] = xv;
      *(float4*)&hss[r][c4] = gv;
    }
    if (tid < 16) flags[tid] = (tid < nrows) ? haschild[row0 + tid] : 0;
    __syncthreads();
    if (tid == 0) { int a = 0; for (int r = 0; r < nrows; ++r) a |= flags[r]; s_any = a; }
    __syncthreads();
    float acc[3][2][4];
    #pragma unroll
    for (int ci = 0; ci < 3; ++ci)
      #pragma unroll
      for (int g = 0; g < 2; ++g)
        #pragma unroll
        for (int q = 0; q < 4; ++q) acc[ci][g][q] = 0.f;
    if (s_any) {
      for (int ci = 0; ci < 3; ++ci) {
        for (int kc = 0; kc < 2; ++kc) {
          __syncthreads();
          for (int idx = tid; idx < 64 * DIM / 4; idx += 256) {
            int r = idx >> 5, c4 = (idx & 31) * 4;
            *(float4*)&wsb[r][c4] = *(const float4*)(Wiouh + (size_t)(kc * 64 + r) * (3 * DIM) + ci * DIM + c4);
          }
          __syncthreads();
          #pragma unroll 4
          for (int k = 0; k < 64; ++k) {
            float2 wv = *(const float2*)&wsb[k][2 * c];
            #pragma unroll
            for (int q = 0; q < 4; ++q) {
              float s = hss[rg + q][kc * 64 + k];
              acc[ci][0][q] += s * wv.x; acc[ci][1][q] += s * wv.y;
            }
          }
        }
      }
    }
    #pragma unroll
    for (int q = 0; q < 4; ++q) {
      int r = rg + q;
      if (r < nrows) {
        int gr = row0 + r;
        bool leaf = (flags[r] == 0);
        u32 wi = *(const u32*)(xi + (size_t)gr * 512 +   0 + 2 * c);
        u32 wo = *(const u32*)(xi + (size_t)gr * 512 + 128 + 2 * c);
        u32 wu = *(const u32*)(xi + (size_t)gr * 512 + 256 + 2 * c);
        float2 fcv = *(const float2*)(fcsum + (size_t)gr * DIM + 2 * c);
        float i0 = sigf(bf2f((u16)(wi & 0xffffu)) + acc[0][0][q]);
        float i1 = sigf(bf2f((u16)(wi >> 16))     + acc[0][1][q]);
        float o0 = sigf(bf2f((u16)(wo & 0xffffu)) + acc[1][0][q]);
        float o1 = sigf(bf2f((u16)(wo >> 16))     + acc[1][1][q]);
        float u0 = tanhfast(bf2f((u16)(wu & 0xffffu)) + acc[2][0][q]);
        float u1 = tanhfast(bf2f((u16)(wu >> 16))     + acc[2][1][q]);
        float ci0 = fcv.x + i0 * u0, ci1 = fcv.y + i1 * u1;
        float xv0 = xs[r][2 * c], xv1 = xs[r][2 * c + 1];
        float hv0 = leaf ? xv0 : o0 * tanhfast(ci0);
        float hv1 = leaf ? xv1 : o1 * tanhfast(ci1);
        float cv0 = leaf ? tanhfast(xv0) : ci0;
        float cv1 = leaf ? tanhfast(xv1) : ci1;
        float2 hst; hst.x = hv0; hst.y = hv1;
        *(float2*)(h + (size_t)gr * DIM + 2 * c) = hst;
        float2 cst; cst.x = cv0; cst.y = cv1;
        *(float2*)(cbuf + (size_t)gr * DIM + 2 * c) = cst;
      }
    }
    __syncthreads();
  }
}

extern "C" void kernel_launch(void* const* d_in, const int* in_sizes, int n_in,
                              void* d_out, int out_size, void* d_ws, size_t ws_size,
                              hipStream_t stream) {
  const float* x    = (const float*)d_in[0];
  const int* parent = (const int*)d_in[1];
  const int* depth  = (const int*)d_in[2];
  const float* Wioux = (const float*)d_in[3];
  const float* Wiouh = (const float*)d_in[4];
  const float* Wfx   = (const float*)d_in[5];
  const float* Wfh   = (const float*)d_in[6];
  int n = in_sizes[0] / DIM;
  float* h = (float*)d_out;

  u16*   WcT  = (u16*)d_ws;                           // 512*128 bf16
  u16*   xi   = WcT + 512 * 128;                      // n*512 bf16
  float* cbuf = (float*)(xi + (size_t)n * 512);       // n*128 f32
  float* hsum = cbuf + (size_t)n * DIM;               // n*128 f32
  float* fcsum = hsum + (size_t)n * DIM;              // n*128 f32
  int*   haschild = (int*)(fcsum + (size_t)n * DIM);  // n int
  int*   ofs  = haschild + n;

  // zero hsum, fcsum, haschild (contiguous)
  hipMemsetAsync(hsum, 0, (size_t)2 * n * DIM * sizeof(float) + (size_t)n * sizeof(int), stream);
  k_prep<<<(512 * 128 + 255) / 256, 256, 0, stream>>>(Wioux, Wfx, WcT);
  k_levels<<<1, 32, 0, stream>>>(depth, n, ofs);
  k_mark<<<(n + 255) / 256, 256, 0, stream>>>(parent, n, haschild);
  dim3 gb((n + 63) / 64, 4);
  k_big<<<gb, 256, 0, stream>>>(x, WcT, xi, n);

  for (int d = LVL - 1; d >= 0; --d) {
    if (d < LVL - 1)
      k_child<<<1024, 256, 0, stream>>>(h, cbuf, xi, Wfh, parent, ofs, hsum, fcsum, d);
    k_node<<<1024, 256, 0, stream>>>(x, Wiouh, xi, hsum, fcsum, haschild, ofs, h, cbuf, d);
  }
}

// Round 4
// 405.511 us; speedup vs baseline: 1.8946x; 1.3670x over previous
//
#include <hip/hip_runtime.h>
#include <hip/hip_bf16.h>

#define DIM 128
#define LVL 8

typedef unsigned int u32;
typedef unsigned short u16;

using bf16x8 = __attribute__((ext_vector_type(8))) short;
using f32x4  = __attribute__((ext_vector_type(4))) float;

__device__ __forceinline__ float bf2f(u16 u) { union { u32 i; float f; } v; v.i = ((u32)u) << 16; return v.f; }
__device__ __forceinline__ u16 f2bf(float f) { __hip_bfloat16 b = __float2bfloat16(f); return *reinterpret_cast<u16*>(&b); }
__device__ __forceinline__ u32 pk2(float lo, float hi) { return (u32)f2bf(lo) | ((u32)f2bf(hi) << 16); }
__device__ __forceinline__ float sigf(float x) { return 1.f / (1.f + __expf(-x)); }
__device__ __forceinline__ float tanhfast(float x) { return 1.f - 2.f / (__expf(2.f * x) + 1.f); }

// ---- level offsets: ofs[d] = first index with depth >= d ----
__global__ void k_levels(const int* __restrict__ depth, int n, int* __restrict__ ofs) {
  int d = threadIdx.x;
  if (d > LVL) return;
  int lo = 0, hi = n;
  while (lo < hi) { int mid = (lo + hi) >> 1; if (depth[mid] < d) lo = mid + 1; else hi = mid; }
  ofs[d] = lo;
}

// ---- haschild via benign-race plain store ----
__global__ void k_mark(const int* __restrict__ parent, int n, int* __restrict__ haschild) {
  int j = blockIdx.x * blockDim.x + threadIdx.x;
  if (j >= n) return;
  int p = parent[j];
  if (p >= 0 && p < n) haschild[p] = 1;
}

// ---- bf16 transposed weights:
// WcT [512][128]  = cols of [Wioux | Wfx]
// WhT [384][128]  = cols of Wiouh
// WfhT[128][128]  = cols of Wfh
__global__ void k_prep(const float* __restrict__ Wioux, const float* __restrict__ Wiouh,
                       const float* __restrict__ Wfx, const float* __restrict__ Wfh,
                       u16* __restrict__ WcT, u16* __restrict__ WhT, u16* __restrict__ WfhT) {
  int i = blockIdx.x * 256 + threadIdx.x;
  if (i >= 1024 * 128) return;
  int c = i >> 7, k = i & 127;
  float v; u16* dst;
  if (c < 512) {
    v = (c < 384) ? Wioux[(size_t)k * 384 + c] : Wfx[(size_t)k * 128 + (c - 384)];
    dst = &WcT[(size_t)c * 128 + k];
  } else if (c < 896) {
    int cc = c - 512; v = Wiouh[(size_t)k * 384 + cc]; dst = &WhT[(size_t)cc * 128 + k];
  } else {
    int cc = c - 896; v = Wfh[(size_t)k * 128 + cc]; dst = &WfhT[(size_t)cc * 128 + k];
  }
  *dst = f2bf(v);
}

// ---- xi = x @ [Wioux|Wfx] (MFMA bf16). One block per 64 rows, loops all 4 col chunks.
// Stores only rows with children (leaf xi never read). All-leaf tiles exit early.
__global__ __launch_bounds__(256) void k_big(const float* __restrict__ x, const u16* __restrict__ WcT,
                                             const int* __restrict__ haschild, u16* __restrict__ xi, int n) {
  __shared__ __align__(16) char smem[16384 + 32768];
  char* xsb = smem;                      // 64x128 bf16 swizzled
  char* wtb = smem + 16384;              // 128x128 bf16 swizzled (aliased by dbuf)
  u16* dbuf = (u16*)(smem + 16384);      // [64][136]
  __shared__ int s_any;
  int tid = threadIdx.x;
  int wave = tid >> 6, lane = tid & 63, m = lane & 15, kg = lane >> 4;
  int row0 = blockIdx.x * 64;
  if (tid == 0) {
    int a = 0;
    for (int r = 0; r < 64 && row0 + r < n; ++r) a |= haschild[row0 + r];
    s_any = a;
  }
  __syncthreads();
  if (!s_any) return;
  for (int i = tid; i < 64 * 16; i += 256) {
    int r = i >> 4, c8 = (i & 15) * 8;
    int gr = row0 + r;
    uint4 o = make_uint4(0u, 0u, 0u, 0u);
    if (gr < n) {
      float4 a = *(const float4*)(x + (size_t)gr * DIM + c8);
      float4 b = *(const float4*)(x + (size_t)gr * DIM + c8 + 4);
      o = make_uint4(pk2(a.x, a.y), pk2(a.z, a.w), pk2(b.x, b.y), pk2(b.z, b.w));
    }
    *(uint4*)(xsb + r * 256 + ((c8 * 2) ^ ((r & 7) << 4))) = o;
  }
  int arow = wave * 16 + m;
  for (int ci = 0; ci < 4; ++ci) {
    __syncthreads();
    for (int i = tid; i < 128 * 16; i += 256) {
      int cl = i >> 4, k8 = (i & 15) * 8;
      uint4 v = *(const uint4*)(WcT + (size_t)(ci * 128 + cl) * 128 + k8);
      *(uint4*)(wtb + cl * 256 + ((k8 * 2) ^ ((cl & 7) << 4))) = v;
    }
    __syncthreads();
    f32x4 acc[8];
    #pragma unroll
    for (int nt = 0; nt < 8; ++nt) acc[nt] = (f32x4){0.f, 0.f, 0.f, 0.f};
    #pragma unroll
    for (int kk = 0; kk < 4; ++kk) {
      int kbyte = kk * 64 + kg * 16;
      bf16x8 a = *(const bf16x8*)(xsb + arow * 256 + (kbyte ^ ((arow & 7) << 4)));
      #pragma unroll
      for (int nt = 0; nt < 8; ++nt) {
        int col = nt * 16 + m;
        bf16x8 b = *(const bf16x8*)(wtb + col * 256 + (kbyte ^ ((col & 7) << 4)));
        acc[nt] = __builtin_amdgcn_mfma_f32_16x16x32_bf16(a, b, acc[nt], 0, 0, 0);
      }
    }
    __syncthreads();
    #pragma unroll
    for (int nt = 0; nt < 8; ++nt)
      #pragma unroll
      for (int r = 0; r < 4; ++r)
        dbuf[(wave * 16 + kg * 4 + r) * 136 + nt * 16 + m] = f2bf(acc[nt][r]);
    __syncthreads();
    int r2 = tid >> 2, q = tid & 3;
    int gr = row0 + r2;
    if (gr < n && haschild[gr]) {
      const u16* src = dbuf + r2 * 136 + q * 32;
      u16* dst = xi + (size_t)gr * 512 + ci * 128 + q * 32;
      #pragma unroll
      for (int seg = 0; seg < 4; ++seg)
        *(uint4*)(dst + seg * 8) = *(const uint4*)(src + seg * 8);
    }
  }
}

// ---- per child (depth d+1): f_pre = h@Wfh (MFMA); f=sig(xf[p]+f_pre);
//      hsum[p]+=h; fcsum[p]+=f*c.  64-row tiles; block-reduced path when single parent.
__global__ __launch_bounds__(256) void k_child(const float* __restrict__ h, const float* __restrict__ cbuf,
    const u16* __restrict__ xi, const u16* __restrict__ WfhT, const int* __restrict__ parent,
    const int* __restrict__ ofs, float* __restrict__ hsum, float* __restrict__ fcsum, int d) {
  __shared__ __align__(16) char smem[16384 + 33792];
  char* hsb = smem;                      // 64x128 bf16 swizzled
  char* wtb = smem + 16384;              // 128x128 bf16 swizzled
  float* dbuf = (float*)(smem + 16384);  // [64][132] f32 (aliases wtb after MFMA)
  __shared__ int ps[64];
  __shared__ int s_uni;
  int c0 = ofs[d + 1], c1 = ofs[d + 2];
  int tid = threadIdx.x;
  int wave = tid >> 6, lane = tid & 63, m = lane & 15, kg = lane >> 4;
  int arow = wave * 16 + m;
  for (int row0 = c0 + (int)blockIdx.x * 64; row0 < c1; row0 += (int)gridDim.x * 64) {
    int nrows = min(64, c1 - row0);
    if (tid < 64) ps[tid] = (tid < nrows) ? parent[row0 + tid] : -1;
    for (int i = tid; i < 64 * 16; i += 256) {
      int r = i >> 4, c8 = (i & 15) * 8;
      uint4 o = make_uint4(0u, 0u, 0u, 0u);
      if (r < nrows) {
        const float* hp = h + (size_t)(row0 + r) * DIM + c8;
        float4 a = *(const float4*)hp; float4 b = *(const float4*)(hp + 4);
        o = make_uint4(pk2(a.x, a.y), pk2(a.z, a.w), pk2(b.x, b.y), pk2(b.z, b.w));
      }
      *(uint4*)(hsb + r * 256 + ((c8 * 2) ^ ((r & 7) << 4))) = o;
    }
    __syncthreads();
    if (tid == 0) {
      int u = 1, p0 = ps[0];
      for (int r = 1; r < nrows; ++r) if (ps[r] != p0) { u = 0; break; }
      s_uni = u;
    }
    for (int i = tid; i < 128 * 16; i += 256) {
      int cl = i >> 4, k8 = (i & 15) * 8;
      uint4 v = *(const uint4*)(WfhT + (size_t)cl * 128 + k8);
      *(uint4*)(wtb + cl * 256 + ((k8 * 2) ^ ((cl & 7) << 4))) = v;
    }
    __syncthreads();
    f32x4 acc[8];
    #pragma unroll
    for (int nt = 0; nt < 8; ++nt) acc[nt] = (f32x4){0.f, 0.f, 0.f, 0.f};
    #pragma unroll
    for (int kk = 0; kk < 4; ++kk) {
      int kbyte = kk * 64 + kg * 16;
      bf16x8 a = *(const bf16x8*)(hsb + arow * 256 + (kbyte ^ ((arow & 7) << 4)));
      #pragma unroll
      for (int nt = 0; nt < 8; ++nt) {
        int col = nt * 16 + m;
        bf16x8 b = *(const bf16x8*)(wtb + col * 256 + (kbyte ^ ((col & 7) << 4)));
        acc[nt] = __builtin_amdgcn_mfma_f32_16x16x32_bf16(a, b, acc[nt], 0, 0, 0);
      }
    }
    __syncthreads();   // MFMA consumed wtb; s_uni visible
    if (s_uni) {
      int p = ps[0];
      #pragma unroll
      for (int nt = 0; nt < 8; ++nt) {
        int col = nt * 16 + m;
        #pragma unroll
        for (int r = 0; r < 4; ++r) {
          int rl = wave * 16 + kg * 4 + r;
          float fc = 0.f;
          if (rl < nrows) {
            float xfv = bf2f(xi[(size_t)p * 512 + 384 + col]);
            float cv = cbuf[(size_t)(row0 + rl) * DIM + col];
            fc = sigf(xfv + acc[nt][r]) * cv;
          }
          dbuf[rl * 132 + col] = fc;
        }
      }
      __syncthreads();
      if (tid < 128) {
        float sh = 0.f, sf = 0.f;
        for (int r = 0; r < 64; ++r) {
          u16 hv = *(const u16*)(hsb + r * 256 + ((2 * tid) ^ ((r & 7) << 4)));
          sh += bf2f(hv);
          sf += dbuf[r * 132 + tid];
        }
        atomicAdd(&hsum[(size_t)p * DIM + tid], sh);
        atomicAdd(&fcsum[(size_t)p * DIM + tid], sf);
      }
      __syncthreads();
    } else {
      #pragma unroll
      for (int nt = 0; nt < 8; ++nt) {
        int col = nt * 16 + m;
        #pragma unroll
        for (int r = 0; r < 4; ++r) {
          int rl = wave * 16 + kg * 4 + r;
          if (rl < nrows) {
            int p = ps[rl];
            float xfv = bf2f(xi[(size_t)p * 512 + 384 + col]);
            float cv = cbuf[(size_t)(row0 + rl) * DIM + col];
            float fc = sigf(xfv + acc[nt][r]) * cv;
            atomicAdd(&fcsum[(size_t)p * DIM + col], fc);
            u16 hv = *(const u16*)(hsb + rl * 256 + ((2 * col) ^ ((rl & 7) << 4)));
            atomicAdd(&hsum[(size_t)p * DIM + col], bf2f(hv));
          }
        }
      }
      __syncthreads();
    }
  }
}

// ---- per node (depth d): iou = xi + hsum@Wiouh (MFMA); gates; leaf override ----
__global__ __launch_bounds__(256) void k_node(const float* __restrict__ x, const u16* __restrict__ WhT,
    const u16* __restrict__ xi, const float* __restrict__ hsum, const float* __restrict__ fcsum,
    const int* __restrict__ haschild, const int* __restrict__ ofs,
    float* __restrict__ h, float* __restrict__ cbuf, int d) {
  __shared__ __align__(16) char smem[16384 + 32768];
  char* hsb = smem;
  char* wtb = smem + 16384;
  __shared__ int flags[64];
  __shared__ int s_any;
  int v0 = ofs[d], v1 = ofs[d + 1];
  int tid = threadIdx.x;
  int wave = tid >> 6, lane = tid & 63, m = lane & 15, kg = lane >> 4;
  int arow = wave * 16 + m;
  for (int row0 = v0 + (int)blockIdx.x * 64; row0 < v1; row0 += (int)gridDim.x * 64) {
    int nrows = min(64, v1 - row0);
    if (tid < 64) flags[tid] = (tid < nrows) ? haschild[row0 + tid] : 0;
    __syncthreads();
    if (tid == 0) { int a = 0; for (int r = 0; r < 64; ++r) a |= flags[r]; s_any = a; }
    __syncthreads();
    if (!s_any) {
      for (int i = tid; i < nrows * 32; i += 256) {
        int r = i >> 5, c4 = (i & 31) * 4;
        int gr = row0 + r;
        float4 xv = *(const float4*)(x + (size_t)gr * DIM + c4);
        float4 cv = make_float4(tanhfast(xv.x), tanhfast(xv.y), tanhfast(xv.z), tanhfast(xv.w));
        *(float4*)(h + (size_t)gr * DIM + c4) = xv;
        *(float4*)(cbuf + (size_t)gr * DIM + c4) = cv;
      }
      __syncthreads();
      continue;
    }
    for (int i = tid; i < 64 * 16; i += 256) {
      int r = i >> 4, c8 = (i & 15) * 8;
      int gr = row0 + r;
      uint4 o = make_uint4(0u, 0u, 0u, 0u);
      if (r < nrows) {
        float4 a = *(const float4*)(hsum + (size_t)gr * DIM + c8);
        float4 b = *(const float4*)(hsum + (size_t)gr * DIM + c8 + 4);
        o = make_uint4(pk2(a.x, a.y), pk2(a.z, a.w), pk2(b.x, b.y), pk2(b.z, b.w));
      }
      *(uint4*)(hsb + r * 256 + ((c8 * 2) ^ ((r & 7) << 4))) = o;
    }
    f32x4 acc[3][8];
    #pragma unroll
    for (int ci = 0; ci < 3; ++ci)
      #pragma unroll
      for (int nt = 0; nt < 8; ++nt) acc[ci][nt] = (f32x4){0.f, 0.f, 0.f, 0.f};
    for (int ci = 0; ci < 3; ++ci) {
      __syncthreads();
      for (int i = tid; i < 128 * 16; i += 256) {
        int cl = i >> 4, k8 = (i & 15) * 8;
        uint4 v = *(const uint4*)(WhT + (size_t)(ci * 128 + cl) * 128 + k8);
        *(uint4*)(wtb + cl * 256 + ((k8 * 2) ^ ((cl & 7) << 4))) = v;
      }
      __syncthreads();
      #pragma unroll
      for (int kk = 0; kk < 4; ++kk) {
        int kbyte = kk * 64 + kg * 16;
        bf16x8 a = *(const bf16x8*)(hsb + arow * 256 + (kbyte ^ ((arow & 7) << 4)));
        #pragma unroll
        for (int nt = 0; nt < 8; ++nt) {
          int col = nt * 16 + m;
          bf16x8 b = *(const bf16x8*)(wtb + col * 256 + (kbyte ^ ((col & 7) << 4)));
          acc[ci][nt] = __builtin_amdgcn_mfma_f32_16x16x32_bf16(a, b, acc[ci][nt], 0, 0, 0);
        }
      }
    }
    #pragma unroll
    for (int nt = 0; nt < 8; ++nt) {
      int col = nt * 16 + m;
      #pragma unroll
      for (int r = 0; r < 4; ++r) {
        int rl = wave * 16 + kg * 4 + r;
        int grow = row0 + rl;
        if (rl >= nrows) continue;
        bool leaf = (flags[rl] == 0);
        float iv = bf2f(xi[(size_t)grow * 512 + col])       + acc[0][nt][r];
        float ov = bf2f(xi[(size_t)grow * 512 + 128 + col]) + acc[1][nt][r];
        float uv = bf2f(xi[(size_t)grow * 512 + 256 + col]) + acc[2][nt][r];
        float fcv = fcsum[(size_t)grow * DIM + col];
        float xv = x[(size_t)grow * DIM + col];
        float ci_ = fcv + sigf(iv) * tanhfast(uv);
        float hv = leaf ? xv : sigf(ov) * tanhfast(ci_);
        float cv = leaf ? tanhfast(xv) : ci_;
        h[(size_t)grow * DIM + col] = hv;
        cbuf[(size_t)grow * DIM + col] = cv;
      }
    }
    __syncthreads();
  }
}

extern "C" void kernel_launch(void* const* d_in, const int* in_sizes, int n_in,
                              void* d_out, int out_size, void* d_ws, size_t ws_size,
                              hipStream_t stream) {
  const float* x    = (const float*)d_in[0];
  const int* parent = (const int*)d_in[1];
  const int* depth  = (const int*)d_in[2];
  const float* Wioux = (const float*)d_in[3];
  const float* Wiouh = (const float*)d_in[4];
  const float* Wfx   = (const float*)d_in[5];
  const float* Wfh   = (const float*)d_in[6];
  int n = in_sizes[0] / DIM;
  float* h = (float*)d_out;

  u16*   WcT  = (u16*)d_ws;                            // 512*128
  u16*   WhT  = WcT + 512 * 128;                       // 384*128
  u16*   WfhT = WhT + 384 * 128;                       // 128*128
  u16*   xi   = WfhT + 128 * 128;                      // n*512
  float* cbuf = (float*)(xi + (size_t)n * 512);        // n*128
  float* hsum = cbuf + (size_t)n * DIM;                // n*128
  float* fcsum = hsum + (size_t)n * DIM;               // n*128
  int*   haschild = (int*)(fcsum + (size_t)n * DIM);   // n
  int*   ofs  = haschild + n;                          // LVL+1

  hipMemsetAsync(hsum, 0, (size_t)2 * n * DIM * sizeof(float) + (size_t)n * sizeof(int), stream);
  k_prep<<<512, 256, 0, stream>>>(Wioux, Wiouh, Wfx, Wfh, WcT, WhT, WfhT);
  k_levels<<<1, 32, 0, stream>>>(depth, n, ofs);
  k_mark<<<(n + 255) / 256, 256, 0, stream>>>(parent, n, haschild);
  k_big<<<(n + 63) / 64, 256, 0, stream>>>(x, WcT, haschild, xi, n);

  for (int d = LVL - 1; d >= 0; --d) {
    if (d < LVL - 1)
      k_child<<<160, 256, 0, stream>>>(h, cbuf, xi, WfhT, parent, ofs, hsum, fcsum, d);
    k_node<<<160, 256, 0, stream>>>(x, WhT, xi, hsum, fcsum, haschild, ofs, h, cbuf, d);
  }
}

// Round 5
// 389.863 us; speedup vs baseline: 1.9706x; 1.0401x over previous
//
#include <hip/hip_runtime.h>
#include <hip/hip_bf16.h>

#define DIM 128
#define LVL 8

typedef unsigned int u32;
typedef unsigned short u16;

using bf16x8 = __attribute__((ext_vector_type(8))) short;
using f32x4  = __attribute__((ext_vector_type(4))) float;

__device__ __forceinline__ float bf2f(u16 u) { union { u32 i; float f; } v; v.i = ((u32)u) << 16; return v.f; }
__device__ __forceinline__ u16 f2bf(float f) { __hip_bfloat16 b = __float2bfloat16(f); return *reinterpret_cast<u16*>(&b); }
__device__ __forceinline__ u32 pk2(float lo, float hi) { return (u32)f2bf(lo) | ((u32)f2bf(hi) << 16); }
__device__ __forceinline__ float sigf(float x) { return 1.f / (1.f + __expf(-x)); }
__device__ __forceinline__ float tanhfast(float x) { return 1.f - 2.f / (__expf(2.f * x) + 1.f); }

// ---- level offsets: ofs[d] = first index with depth >= d ----
__global__ void k_levels(const int* __restrict__ depth, int n, int* __restrict__ ofs) {
  int d = threadIdx.x;
  if (d > LVL) return;
  int lo = 0, hi = n;
  while (lo < hi) { int mid = (lo + hi) >> 1; if (depth[mid] < d) lo = mid + 1; else hi = mid; }
  ofs[d] = lo;
}

// ---- haschild via benign-race plain store ----
__global__ void k_mark(const int* __restrict__ parent, int n, int* __restrict__ haschild) {
  int j = blockIdx.x * blockDim.x + threadIdx.x;
  if (j >= n) return;
  int p = parent[j];
  if (p >= 0 && p < n) haschild[p] = 1;
}

// ---- bf16 transposed weights ----
__global__ void k_prep(const float* __restrict__ Wioux, const float* __restrict__ Wiouh,
                       const float* __restrict__ Wfx, const float* __restrict__ Wfh,
                       u16* __restrict__ WcT, u16* __restrict__ WhT, u16* __restrict__ WfhT) {
  int i = blockIdx.x * 256 + threadIdx.x;
  if (i >= 1024 * 128) return;
  int c = i >> 7, k = i & 127;
  float v; u16* dst;
  if (c < 512) {
    v = (c < 384) ? Wioux[(size_t)k * 384 + c] : Wfx[(size_t)k * 128 + (c - 384)];
    dst = &WcT[(size_t)c * 128 + k];
  } else if (c < 896) {
    int cc = c - 512; v = Wiouh[(size_t)k * 384 + cc]; dst = &WhT[(size_t)cc * 128 + k];
  } else {
    int cc = c - 896; v = Wfh[(size_t)k * 128 + cc]; dst = &WfhT[(size_t)cc * 128 + k];
  }
  *dst = f2bf(v);
}

// ---- xi = x @ [Wioux|Wfx] (MFMA bf16), W-chunk register prefetch pipeline ----
__global__ __launch_bounds__(256) void k_big(const float* __restrict__ x, const u16* __restrict__ WcT,
                                             const int* __restrict__ haschild, u16* __restrict__ xi, int n) {
  __shared__ __align__(16) char smem[16384 + 32768];
  char* xsb = smem;                      // 64x128 bf16 swizzled
  char* wtb = smem + 16384;              // 128x128 bf16 swizzled
  u16* dbuf = (u16*)(smem + 16384);      // [64][136] (aliases wtb)
  __shared__ int s_any;
  int tid = threadIdx.x;
  int wave = tid >> 6, lane = tid & 63, m = lane & 15, kg = lane >> 4;
  int row0 = blockIdx.x * 64;
  if (tid == 0) {
    int a = 0;
    for (int r = 0; r < 64 && row0 + r < n; ++r) a |= haschild[row0 + r];
    s_any = a;
  }
  __syncthreads();
  if (!s_any) return;
  for (int i = tid; i < 64 * 16; i += 256) {
    int r = i >> 4, c8 = (i & 15) * 8;
    int gr = row0 + r;
    uint4 o = make_uint4(0u, 0u, 0u, 0u);
    if (gr < n) {
      float4 a = *(const float4*)(x + (size_t)gr * DIM + c8);
      float4 b = *(const float4*)(x + (size_t)gr * DIM + c8 + 4);
      o = make_uint4(pk2(a.x, a.y), pk2(a.z, a.w), pk2(b.x, b.y), pk2(b.z, b.w));
    }
    *(uint4*)(xsb + r * 256 + ((c8 * 2) ^ ((r & 7) << 4))) = o;
  }
  int arow = wave * 16 + m;
  uint4 wreg[8];
  #pragma unroll
  for (int j = 0; j < 8; ++j) {
    int i = tid + j * 256;
    wreg[j] = *(const uint4*)(WcT + (size_t)(i >> 4) * 128 + (i & 15) * 8);
  }
  for (int ci = 0; ci < 4; ++ci) {
    __syncthreads();                      // wtb/dbuf free, xsb staged
    #pragma unroll
    for (int j = 0; j < 8; ++j) {
      int i = tid + j * 256;
      int cl = i >> 4, k8 = (i & 15) * 8;
      *(uint4*)(wtb + cl * 256 + ((k8 * 2) ^ ((cl & 7) << 4))) = wreg[j];
    }
    __syncthreads();
    if (ci < 3) {                         // prefetch next chunk; lands during MFMA+epilogue
      #pragma unroll
      for (int j = 0; j < 8; ++j) {
        int i = tid + j * 256;
        wreg[j] = *(const uint4*)(WcT + (size_t)((ci + 1) * 128 + (i >> 4)) * 128 + (i & 15) * 8);
      }
    }
    f32x4 acc[8];
    #pragma unroll
    for (int nt = 0; nt < 8; ++nt) acc[nt] = (f32x4){0.f, 0.f, 0.f, 0.f};
    #pragma unroll
    for (int kk = 0; kk < 4; ++kk) {
      int kbyte = kk * 64 + kg * 16;
      bf16x8 a = *(const bf16x8*)(xsb + arow * 256 + (kbyte ^ ((arow & 7) << 4)));
      #pragma unroll
      for (int nt = 0; nt < 8; ++nt) {
        int col = nt * 16 + m;
        bf16x8 b = *(const bf16x8*)(wtb + col * 256 + (kbyte ^ ((col & 7) << 4)));
        acc[nt] = __builtin_amdgcn_mfma_f32_16x16x32_bf16(a, b, acc[nt], 0, 0, 0);
      }
    }
    __syncthreads();
    #pragma unroll
    for (int nt = 0; nt < 8; ++nt)
      #pragma unroll
      for (int r = 0; r < 4; ++r)
        dbuf[(wave * 16 + kg * 4 + r) * 136 + nt * 16 + m] = f2bf(acc[nt][r]);
    __syncthreads();
    int r2 = tid >> 2, q = tid & 3;
    int gr = row0 + r2;
    if (gr < n && haschild[gr]) {
      const u16* src = dbuf + r2 * 136 + q * 32;
      u16* dst = xi + (size_t)gr * 512 + ci * 128 + q * 32;
      #pragma unroll
      for (int seg = 0; seg < 4; ++seg)
        *(uint4*)(dst + seg * 8) = *(const uint4*)(src + seg * 8);
    }
  }
}

// ---- fused per-level kernel: gates for level-d rows + scatter into level d-1 parents ----
__global__ __launch_bounds__(256) void k_level(const float* __restrict__ x,
    const u16* __restrict__ WhT, const u16* __restrict__ WfhT, const u16* __restrict__ xi,
    const int* __restrict__ haschild, const int* __restrict__ parent,
    const int* __restrict__ ofs, float* __restrict__ hout,
    float* hsum, float* fcsum, int d) {
  __shared__ __align__(16) char smem[16384 + 33792];
  char* hsb = smem;                      // 64x128 bf16 swizzled (hsum-bf16, then h-bf16)
  char* wtb = smem + 16384;              // 128x128 bf16 swizzled W chunk
  float* dbuf = (float*)(smem + 16384);  // [64][132] f32 (aliases wtb)
  __shared__ int ps[64];
  __shared__ int flags[64];
  __shared__ int s_uni, s_anyp;
  int v0 = ofs[d], v1 = ofs[d + 1];
  int tid = threadIdx.x;
  int wave = tid >> 6, lane = tid & 63, m = lane & 15, kg = lane >> 4;
  int arow = wave * 16 + m;
  for (int row0 = v0 + (int)blockIdx.x * 64; row0 < v1; row0 += (int)gridDim.x * 64) {
    int nrows = min(64, v1 - row0);
    if (tid < 64) {
      flags[tid] = (tid < nrows) ? haschild[row0 + tid] : 0;
      ps[tid] = (tid < nrows) ? parent[row0 + tid] : -1;
    }
    __syncthreads();
    if (tid == 0) {
      int a = 0; for (int r = 0; r < 64; ++r) a |= flags[r];
      s_anyp = a;
      int u = 1, p0 = ps[0];
      for (int r = 1; r < nrows; ++r) if (ps[r] != p0) { u = 0; break; }
      s_uni = u;
    }
    __syncthreads();
    f32x4 acc[3][8];
    #pragma unroll
    for (int ci = 0; ci < 3; ++ci)
      #pragma unroll
      for (int nt = 0; nt < 8; ++nt) acc[ci][nt] = (f32x4){0.f, 0.f, 0.f, 0.f};
    if (s_anyp) {
      // stage hsum rows as bf16 swizzled
      for (int i = tid; i < 64 * 16; i += 256) {
        int r = i >> 4, c8 = (i & 15) * 8;
        uint4 o = make_uint4(0u, 0u, 0u, 0u);
        if (r < nrows) {
          const float* hp = hsum + (size_t)(row0 + r) * DIM + c8;
          float4 a = *(const float4*)hp; float4 b = *(const float4*)(hp + 4);
          o = make_uint4(pk2(a.x, a.y), pk2(a.z, a.w), pk2(b.x, b.y), pk2(b.z, b.w));
        }
        *(uint4*)(hsb + r * 256 + ((c8 * 2) ^ ((r & 7) << 4))) = o;
      }
      #pragma unroll
      for (int ci = 0; ci < 3; ++ci) {
        for (int i = tid; i < 128 * 16; i += 256) {
          int cl = i >> 4, k8 = (i & 15) * 8;
          uint4 v = *(const uint4*)(WhT + (size_t)(ci * 128 + cl) * 128 + k8);
          *(uint4*)(wtb + cl * 256 + ((k8 * 2) ^ ((cl & 7) << 4))) = v;
        }
        __syncthreads();
        #pragma unroll
        for (int kk = 0; kk < 4; ++kk) {
          int kbyte = kk * 64 + kg * 16;
          bf16x8 a = *(const bf16x8*)(hsb + arow * 256 + (kbyte ^ ((arow & 7) << 4)));
          #pragma unroll
          for (int nt = 0; nt < 8; ++nt) {
            int col = nt * 16 + m;
            bf16x8 b = *(const bf16x8*)(wtb + col * 256 + (kbyte ^ ((col & 7) << 4)));
            acc[ci][nt] = __builtin_amdgcn_mfma_f32_16x16x32_bf16(a, b, acc[ci][nt], 0, 0, 0);
          }
        }
        __syncthreads();                  // wtb free; after last ci: hsb free too
      }
    }
    // epilogue: gates -> h,c ; h to global ; h-bf16 into hsb for the Wfh MFMA
    float cc[8][4];
    #pragma unroll
    for (int nt = 0; nt < 8; ++nt) {
      int col = nt * 16 + m;
      #pragma unroll
      for (int r = 0; r < 4; ++r) {
        int rl = wave * 16 + kg * 4 + r;
        int grow = row0 + rl;
        float hv = 0.f, cv = 0.f;
        if (rl < nrows) {
          bool leaf = (flags[rl] == 0);
          float xv = x[(size_t)grow * DIM + col];
          float iv = bf2f(xi[(size_t)grow * 512 + col])       + acc[0][nt][r];
          float ov = bf2f(xi[(size_t)grow * 512 + 128 + col]) + acc[1][nt][r];
          float uv = bf2f(xi[(size_t)grow * 512 + 256 + col]) + acc[2][nt][r];
          float fcv = fcsum[(size_t)grow * DIM + col];
          float ci_ = fcv + sigf(iv) * tanhfast(uv);
          hv = leaf ? xv : sigf(ov) * tanhfast(ci_);
          cv = leaf ? tanhfast(xv) : ci_;
          hout[(size_t)grow * DIM + col] = hv;
        }
        cc[nt][r] = cv;
        if (d > 0) *(u16*)(hsb + rl * 256 + ((2 * col) ^ ((rl & 7) << 4))) = f2bf(hv);
      }
    }
    if (d > 0) {
      // stage WfhT (wtb region; disjoint from hsb writes above)
      for (int i = tid; i < 128 * 16; i += 256) {
        int cl = i >> 4, k8 = (i & 15) * 8;
        uint4 v = *(const uint4*)(WfhT + (size_t)cl * 128 + k8);
        *(uint4*)(wtb + cl * 256 + ((k8 * 2) ^ ((cl & 7) << 4))) = v;
      }
      __syncthreads();                    // hsb(h) + wtb(Wfh) ready
      f32x4 fp[8];
      #pragma unroll
      for (int nt = 0; nt < 8; ++nt) fp[nt] = (f32x4){0.f, 0.f, 0.f, 0.f};
      #pragma unroll
      for (int kk = 0; kk < 4; ++kk) {
        int kbyte = kk * 64 + kg * 16;
        bf16x8 a = *(const bf16x8*)(hsb + arow * 256 + (kbyte ^ ((arow & 7) << 4)));
        #pragma unroll
        for (int nt = 0; nt < 8; ++nt) {
          int col = nt * 16 + m;
          bf16x8 b = *(const bf16x8*)(wtb + col * 256 + (kbyte ^ ((col & 7) << 4)));
          fp[nt] = __builtin_amdgcn_mfma_f32_16x16x32_bf16(a, b, fp[nt], 0, 0, 0);
        }
      }
      __syncthreads();                    // wtb consumed; dbuf (alias) writable
      if (s_uni) {
        int p = ps[0];
        #pragma unroll
        for (int nt = 0; nt < 8; ++nt) {
          int col = nt * 16 + m;
          float xfv = bf2f(xi[(size_t)p * 512 + 384 + col]);
          #pragma unroll
          for (int r = 0; r < 4; ++r) {
            int rl = wave * 16 + kg * 4 + r;
            float fc = (rl < nrows) ? sigf(xfv + fp[nt][r]) * cc[nt][r] : 0.f;
            dbuf[rl * 132 + col] = fc;
          }
        }
        __syncthreads();
        if (tid < 128) {
          float sh = 0.f, sf = 0.f;
          for (int r = 0; r < 64; ++r) {
            sh += bf2f(*(const u16*)(hsb + r * 256 + ((2 * tid) ^ ((r & 7) << 4))));
            sf += dbuf[r * 132 + tid];
          }
          atomicAdd(&hsum[(size_t)p * DIM + tid], sh);
          atomicAdd(&fcsum[(size_t)p * DIM + tid], sf);
        }
        __syncthreads();
      } else {
        #pragma unroll
        for (int nt = 0; nt < 8; ++nt) {
          int col = nt * 16 + m;
          #pragma unroll
          for (int r = 0; r < 4; ++r) {
            int rl = wave * 16 + kg * 4 + r;
            if (rl < nrows) {
              int p = ps[rl];
              float xfv = bf2f(xi[(size_t)p * 512 + 384 + col]);
              float fc = sigf(xfv + fp[nt][r]) * cc[nt][r];
              atomicAdd(&fcsum[(size_t)p * DIM + col], fc);
              float hvv = bf2f(*(const u16*)(hsb + rl * 256 + ((2 * col) ^ ((rl & 7) << 4))));
              atomicAdd(&hsum[(size_t)p * DIM + col], hvv);
            }
          }
        }
        __syncthreads();
      }
    } else {
      __syncthreads();
    }
  }
}

extern "C" void kernel_launch(void* const* d_in, const int* in_sizes, int n_in,
                              void* d_out, int out_size, void* d_ws, size_t ws_size,
                              hipStream_t stream) {
  const float* x    = (const float*)d_in[0];
  const int* parent = (const int*)d_in[1];
  const int* depth  = (const int*)d_in[2];
  const float* Wioux = (const float*)d_in[3];
  const float* Wiouh = (const float*)d_in[4];
  const float* Wfx   = (const float*)d_in[5];
  const float* Wfh   = (const float*)d_in[6];
  int n = in_sizes[0] / DIM;
  float* h = (float*)d_out;

  u16*   WcT  = (u16*)d_ws;                            // 512*128
  u16*   WhT  = WcT + 512 * 128;                       // 384*128
  u16*   WfhT = WhT + 384 * 128;                       // 128*128
  u16*   xi   = WfhT + 128 * 128;                      // n*512
  float* hsum = (float*)(xi + (size_t)n * 512);        // n*128
  float* fcsum = hsum + (size_t)n * DIM;               // n*128
  int*   haschild = (int*)(fcsum + (size_t)n * DIM);   // n
  int*   ofs  = haschild + n;                          // LVL+1

  hipMemsetAsync(hsum, 0, (size_t)2 * n * DIM * sizeof(float) + (size_t)n * sizeof(int), stream);
  k_prep<<<512, 256, 0, stream>>>(Wioux, Wiouh, Wfx, Wfh, WcT, WhT, WfhT);
  k_levels<<<1, 32, 0, stream>>>(depth, n, ofs);
  k_mark<<<(n + 255) / 256, 256, 0, stream>>>(parent, n, haschild);
  k_big<<<(n + 63) / 64, 256, 0, stream>>>(x, WcT, haschild, xi, n);

  for (int d = LVL - 1; d >= 0; --d)
    k_level<<<256, 256, 0, stream>>>(x, WhT, WfhT, xi, haschild, parent, ofs, h, hsum, fcsum, d);
}